// Round 1
// baseline (347.648 us; speedup 1.0000x reference)
//
#include <hip/hip_runtime.h>
#include <hip/hip_bf16.h>
#include <stdint.h>

#define NUM_B 4
#define NUM_C 192
#define NUM_C2 384
#define NUM_H 128
#define NUM_W 128
#define NUM_N 16384
#define NHEADS 8
#define CHD 24

typedef float f32x4_t __attribute__((ext_vector_type(4)));
typedef float f32x2_t __attribute__((ext_vector_type(2)));
typedef __bf16 bf16x8_t __attribute__((ext_vector_type(8)));
typedef unsigned short u16x8_t __attribute__((ext_vector_type(8)));

__device__ __forceinline__ float bf2f(unsigned short u){
  union { unsigned int i; float f; } v; v.i = ((unsigned int)u) << 16; return v.f;
}
__device__ __forceinline__ unsigned short f2bf(float f){
  union { float f; unsigned int i; } v; v.f = f;
  unsigned int x = v.i;
  x += 0x7fffu + ((x >> 16) & 1u);   // round-to-nearest-even
  return (unsigned short)(x >> 16);
}

// ---------------------------------------------------------------------------
// Kernel 1: conv1x1 as MFMA GEMM.  Z[b][o][n] = sum_c W[o][c]*I[b][c][n] + bias[o]
// Tile 128(o) x 128(n), BK=32, double-buffered LDS, fp32->bf16 on the fly.
// LDS rows are 40 shorts (80B): 16B-aligned chunks, chunk-XOR swizzle -> ~2-way
// bank conflicts max on ds_read_b128 / ds_write_b128.
// ---------------------------------------------------------------------------
#define LROW 40

template<int ADD2>
__global__ __launch_bounds__(256, 2) void conv1x1_gemm(
    const float* __restrict__ inA, const float* __restrict__ inB,
    const float* __restrict__ Wf, const float* __restrict__ bias,
    unsigned short* __restrict__ zout)
{
  __shared__ unsigned short As[2][128 * LROW];
  __shared__ unsigned short Bs[2][128 * LROW];
  const int t = threadIdx.x;
  const int lane = t & 63;
  const int wid = t >> 6;
  const int wr = wid >> 1, wc = wid & 1;
  const int o0 = blockIdx.x * 128;
  const int n0 = blockIdx.y * 128;
  const int b  = blockIdx.z;

  const float* in0 = inA + (size_t)b * NUM_C * NUM_N;
  const float* in1 = ADD2 ? (inB + (size_t)b * NUM_C * NUM_N) : nullptr;

  f32x4_t acc[4][4];
  const f32x4_t zz = {0.f, 0.f, 0.f, 0.f};
  #pragma unroll
  for (int m = 0; m < 4; m++)
    #pragma unroll
    for (int nf = 0; nf < 4; nf++) acc[m][nf] = zz;

  auto stage = [&](int ks, int buf){
    const int k0 = ks * 32;
    // A tile: W rows (o) x 32 k, contiguous in k -> vector loads
    #pragma unroll
    for (int i = 0; i < 2; i++){
      int u = t + 256 * i;
      int o = u >> 2;
      int j = u & 3;
      const float* src = Wf + (size_t)(o0 + o) * NUM_C + k0 + 8 * j;
      f32x4_t f0 = *(const f32x4_t*)src;
      f32x4_t f1 = *(const f32x4_t*)(src + 4);
      u16x8_t pk;
      pk[0] = f2bf(f0[0]); pk[1] = f2bf(f0[1]); pk[2] = f2bf(f0[2]); pk[3] = f2bf(f0[3]);
      pk[4] = f2bf(f1[0]); pk[5] = f2bf(f1[1]); pk[6] = f2bf(f1[2]); pk[7] = f2bf(f1[3]);
      int sw = j ^ ((o >> 3) & 3);
      *(u16x8_t*)(&As[buf][o * LROW + sw * 8]) = pk;
    }
    // B tile: input [c][n] (n contiguous) -> store transposed [n][k]
    // scalar loads, coalesced across lanes (consecutive n)
    #pragma unroll
    for (int i = 0; i < 2; i++){
      int u = t + 256 * i;
      int n = u & 127;
      int j = u >> 7;          // 0..3
      u16x8_t pk;
      #pragma unroll
      for (int jj = 0; jj < 8; jj++){
        int c = k0 + 8 * j + jj;
        float xv = in0[(size_t)c * NUM_N + n0 + n];
        if (ADD2) xv += in1[(size_t)c * NUM_N + n0 + n];
        pk[jj] = f2bf(xv);
      }
      int sw = j ^ ((n >> 3) & 3);
      *(u16x8_t*)(&Bs[buf][n * LROW + sw * 8]) = pk;
    }
  };

  auto compute = [&](int buf){
    bf16x8_t af[4], bfr[4];
    const int rsel = lane & 15;
    const int ksel = lane >> 4;
    #pragma unroll
    for (int m = 0; m < 4; m++){
      int r = wr * 64 + m * 16 + rsel;
      int sw = ksel ^ ((r >> 3) & 3);
      af[m] = *(const bf16x8_t*)(&As[buf][r * LROW + sw * 8]);
    }
    #pragma unroll
    for (int nf = 0; nf < 4; nf++){
      int r = wc * 64 + nf * 16 + rsel;
      int sw = ksel ^ ((r >> 3) & 3);
      bfr[nf] = *(const bf16x8_t*)(&Bs[buf][r * LROW + sw * 8]);
    }
    #pragma unroll
    for (int m = 0; m < 4; m++)
      #pragma unroll
      for (int nf = 0; nf < 4; nf++)
        acc[m][nf] = __builtin_amdgcn_mfma_f32_16x16x32_bf16(af[m], bfr[nf], acc[m][nf], 0, 0, 0);
  };

  stage(0, 0);
  __syncthreads();
  int buf = 0;
  #pragma unroll 1
  for (int ks = 0; ks < 6; ks++){
    if (ks < 5) stage(ks + 1, buf ^ 1);
    compute(buf);
    __syncthreads();
    buf ^= 1;
  }

  const int colb = lane & 15;
  const int rsub = (lane >> 4) * 4;
  #pragma unroll
  for (int m = 0; m < 4; m++){
    #pragma unroll
    for (int nf = 0; nf < 4; nf++){
      int col = n0 + wc * 64 + nf * 16 + colb;
      #pragma unroll
      for (int r = 0; r < 4; r++){
        int o = o0 + wr * 64 + m * 16 + rsub + r;
        float v = acc[m][nf][r] + bias[o];
        zout[((size_t)b * NUM_C2 + o) * NUM_N + col] = f2bf(v);
      }
    }
  }
}

// ---------------------------------------------------------------------------
// Kernel 2: grouped 3x3 conv (groups=192, 2-in/2-out each), SAME zero padding.
// Thread = (group, h, w-octet). Horizontal halo via shfl, vertical via own loads.
// ---------------------------------------------------------------------------
__global__ __launch_bounds__(256) void gconv3_dw(
    const unsigned short* __restrict__ z,
    const float* __restrict__ dww, const float* __restrict__ dwb,
    unsigned short* __restrict__ outq)
{
  const int t = threadIdx.x;
  const int wo = t & 15;
  const int hh = t >> 4;
  const int h = blockIdx.x * 16 + hh;
  const int g = blockIdx.y;
  const int b = blockIdx.z;

  float v[2][3][8];
  #pragma unroll
  for (int ic = 0; ic < 2; ic++){
    const unsigned short* src = z + ((size_t)b * NUM_C2 + 2 * g + ic) * NUM_N;
    #pragma unroll
    for (int dy = 0; dy < 3; dy++){
      int row = h + dy - 1;
      if (row >= 0 && row < NUM_H){
        u16x8_t raw = *(const u16x8_t*)(src + row * NUM_W + wo * 8);
        #pragma unroll
        for (int jj = 0; jj < 8; jj++) v[ic][dy][jj] = bf2f(raw[jj]);
      } else {
        #pragma unroll
        for (int jj = 0; jj < 8; jj++) v[ic][dy][jj] = 0.f;
      }
    }
  }
  float lft[2][3], rgt[2][3];
  #pragma unroll
  for (int ic = 0; ic < 2; ic++)
    #pragma unroll
    for (int dy = 0; dy < 3; dy++){
      float l = __shfl_up(v[ic][dy][7], 1u, 64);
      float r = __shfl_down(v[ic][dy][0], 1u, 64);
      lft[ic][dy] = (wo == 0)  ? 0.f : l;
      rgt[ic][dy] = (wo == 15) ? 0.f : r;
    }
  #pragma unroll
  for (int oc2 = 0; oc2 < 2; oc2++){
    const int oc = 2 * g + oc2;
    float wgt[2][9];
    #pragma unroll
    for (int ic = 0; ic < 2; ic++)
      #pragma unroll
      for (int k9 = 0; k9 < 9; k9++)
        wgt[ic][k9] = dww[(size_t)oc * 18 + ic * 9 + k9];
    float bia = dwb[oc];
    u16x8_t st;
    #pragma unroll
    for (int w8 = 0; w8 < 8; w8++){
      float s = bia;
      #pragma unroll
      for (int ic = 0; ic < 2; ic++)
        #pragma unroll
        for (int ky = 0; ky < 3; ky++)
          #pragma unroll
          for (int kx = 0; kx < 3; kx++){
            int wx = w8 + kx - 1;
            float xv = (wx < 0) ? lft[ic][ky] : ((wx > 7) ? rgt[ic][ky] : v[ic][ky][wx]);
            s += wgt[ic][ky * 3 + kx] * xv;
          }
      st[w8] = f2bf(s);
    }
    *(u16x8_t*)(outq + ((size_t)b * NUM_C2 + oc) * NUM_N + h * NUM_W + wo * 8) = st;
  }
}

// ---------------------------------------------------------------------------
// Kernel 3: fused Gram + norms via MFMA.  For each (b,h):
//   dots1 = q1 @ ky^T, dots2 = q2 @ kx^T  (24x24, K=16384 split over 64 blocks)
//   norms = diag(t @ t^T) for t in {q1,q2,kx,ky}
// A and B fragment layouts coincide, so one loaded fragment serves both roles.
// fp32 atomics accumulate K-split partials.
// ---------------------------------------------------------------------------
__global__ __launch_bounds__(64) void dots_kernel(
    const unsigned short* __restrict__ qkv,
    float* __restrict__ dots1, float* __restrict__ dots2, float* __restrict__ norms)
{
  const int lane = threadIdx.x;
  const int kc = blockIdx.x;   // 64 chunks of 256
  const int h = blockIdx.y;
  const int b = blockIdx.z;
  const unsigned short* q1 = qkv + ((size_t)(0 * NUM_B + b) * NUM_C2 + h * CHD) * NUM_N;
  const unsigned short* q2 = qkv + ((size_t)(0 * NUM_B + b) * NUM_C2 + NUM_C + h * CHD) * NUM_N;
  const unsigned short* kx = qkv + ((size_t)(1 * NUM_B + b) * NUM_C2 + h * CHD) * NUM_N;
  const unsigned short* ky = qkv + ((size_t)(2 * NUM_B + b) * NUM_C2 + h * CHD) * NUM_N;

  const f32x4_t zz = {0.f, 0.f, 0.f, 0.f};
  f32x4_t d1[2][2], d2[2][2], nrm[4][2];
  #pragma unroll
  for (int i = 0; i < 2; i++)
    #pragma unroll
    for (int j = 0; j < 2; j++){ d1[i][j] = zz; d2[i][j] = zz; }
  #pragma unroll
  for (int tn = 0; tn < 4; tn++){ nrm[tn][0] = zz; nrm[tn][1] = zz; }

  const int row = lane & 15;
  const int kl = (lane >> 4) * 8;
  #pragma unroll 1
  for (int ks = 0; ks < 8; ks++){
    const size_t k0 = (size_t)kc * 256 + ks * 32 + kl;
    bf16x8_t fq1[2], fq2[2], fkx[2], fky[2];
    #pragma unroll
    for (int rg = 0; rg < 2; rg++){
      size_t off = (size_t)(rg * 16 + row) * NUM_N + k0;
      fq1[rg] = *(const bf16x8_t*)(q1 + off);
      fq2[rg] = *(const bf16x8_t*)(q2 + off);
      fkx[rg] = *(const bf16x8_t*)(kx + off);
      fky[rg] = *(const bf16x8_t*)(ky + off);
    }
    #pragma unroll
    for (int i = 0; i < 2; i++)
      #pragma unroll
      for (int j = 0; j < 2; j++){
        d1[i][j] = __builtin_amdgcn_mfma_f32_16x16x32_bf16(fq1[i], fky[j], d1[i][j], 0, 0, 0);
        d2[i][j] = __builtin_amdgcn_mfma_f32_16x16x32_bf16(fq2[i], fkx[j], d2[i][j], 0, 0, 0);
      }
    #pragma unroll
    for (int rg = 0; rg < 2; rg++){
      nrm[0][rg] = __builtin_amdgcn_mfma_f32_16x16x32_bf16(fq1[rg], fq1[rg], nrm[0][rg], 0, 0, 0);
      nrm[1][rg] = __builtin_amdgcn_mfma_f32_16x16x32_bf16(fq2[rg], fq2[rg], nrm[1][rg], 0, 0, 0);
      nrm[2][rg] = __builtin_amdgcn_mfma_f32_16x16x32_bf16(fkx[rg], fkx[rg], nrm[2][rg], 0, 0, 0);
      nrm[3][rg] = __builtin_amdgcn_mfma_f32_16x16x32_bf16(fky[rg], fky[rg], nrm[3][rg], 0, 0, 0);
    }
  }

  float* D1 = dots1 + (size_t)(b * NHEADS + h) * CHD * CHD;
  float* D2 = dots2 + (size_t)(b * NHEADS + h) * CHD * CHD;
  float* NB = norms + (size_t)(b * NHEADS + h) * 4 * CHD;
  const int colb = lane & 15;
  const int rb = (lane >> 4) * 4;
  #pragma unroll
  for (int i = 0; i < 2; i++)
    #pragma unroll
    for (int j = 0; j < 2; j++){
      int cc = j * 16 + colb;
      if (cc < CHD){
        #pragma unroll
        for (int r = 0; r < 4; r++){
          int rr = i * 16 + rb + r;
          if (rr < CHD){
            atomicAdd(&D1[rr * CHD + cc], d1[i][j][r]);
            atomicAdd(&D2[rr * CHD + cc], d2[i][j][r]);
          }
        }
      }
    }
  #pragma unroll
  for (int tn = 0; tn < 4; tn++)
    #pragma unroll
    for (int rg = 0; rg < 2; rg++){
      int cc = rg * 16 + colb;
      #pragma unroll
      for (int r = 0; r < 4; r++){
        int rr = rg * 16 + rb + r;
        if (rr == cc && rr < CHD) atomicAdd(&NB[tn * CHD + rr], nrm[tn][rg][r]);
      }
    }
}

// ---------------------------------------------------------------------------
// Kernel 4: cosine-normalize, temperature, softmax -> attn (4,8,24,24) fp32
// ---------------------------------------------------------------------------
__global__ __launch_bounds__(64) void softmax_kernel(
    const float* __restrict__ dots1, const float* __restrict__ dots2,
    const float* __restrict__ norms, const float* __restrict__ temp,
    float* __restrict__ attn)
{
  const int c = threadIdx.x;
  const int bh = blockIdx.x;
  if (c >= CHD) return;
  const int h = bh & 7;
  const float* D1 = dots1 + (size_t)bh * CHD * CHD;
  const float* D2 = dots2 + (size_t)bh * CHD * CHD;
  const float* NB = norms + (size_t)bh * 4 * CHD;
  float n1 = fmaxf(sqrtf(NB[0 * CHD + c]), 1e-12f);
  float n2 = fmaxf(sqrtf(NB[1 * CHD + c]), 1e-12f);
  float T = temp[h];
  float l[CHD];
  float m = -1e30f;
  #pragma unroll
  for (int d = 0; d < CHD; d++){
    float nx = fmaxf(sqrtf(NB[2 * CHD + d]), 1e-12f);  // |kx_d|
    float ny = fmaxf(sqrtf(NB[3 * CHD + d]), 1e-12f);  // |ky_d|
    float e = (D1[c * CHD + d] / (n1 * ny) + D2[c * CHD + d] / (n2 * nx)) * T;
    l[d] = e; m = fmaxf(m, e);
  }
  float s = 0.f;
  #pragma unroll
  for (int d = 0; d < CHD; d++){ float p = expf(l[d] - m); l[d] = p; s += p; }
  float inv = 1.f / s;
  float* A = attn + (size_t)bh * CHD * CHD + c * CHD;
  #pragma unroll
  for (int d = 0; d < CHD; d++) A[d] = l[d] * inv;
}

// ---------------------------------------------------------------------------
// Kernel 5: out = gamma1*attn@vx + gamma2*attn@vy  (streaming, memory-bound)
// ---------------------------------------------------------------------------
__global__ __launch_bounds__(256) void out_kernel(
    const unsigned short* __restrict__ qkv, const float* __restrict__ attn,
    const float* __restrict__ g1, const float* __restrict__ g2,
    float* __restrict__ out)
{
  __shared__ float A[CHD * CHD];
  const int t = threadIdx.x;
  const int nc = blockIdx.x, hq = blockIdx.y, b = blockIdx.z;
  const float* Ag = attn + (size_t)(b * NHEADS + hq) * CHD * CHD;
  for (int i = t; i < CHD * CHD; i += 256) A[i] = Ag[i];
  __syncthreads();
  const int n = nc * 512 + t * 2;
  const unsigned short* vx = qkv + ((size_t)(1 * NUM_B + b) * NUM_C2 + NUM_C + hq * CHD) * NUM_N + n;
  const unsigned short* vy = qkv + ((size_t)(2 * NUM_B + b) * NUM_C2 + NUM_C + hq * CHD) * NUM_N + n;
  float vxa[CHD], vxb[CHD], vya[CHD], vyb[CHD];
  #pragma unroll
  for (int d = 0; d < CHD; d++){
    unsigned int rx = *(const unsigned int*)(vx + (size_t)d * NUM_N);
    unsigned int ry = *(const unsigned int*)(vy + (size_t)d * NUM_N);
    vxa[d] = bf2f((unsigned short)(rx & 0xffffu));
    vxb[d] = bf2f((unsigned short)(rx >> 16));
    vya[d] = bf2f((unsigned short)(ry & 0xffffu));
    vyb[d] = bf2f((unsigned short)(ry >> 16));
  }
  const float G1 = g1[0], G2 = g2[0];
  float* ob = out + ((size_t)b * NUM_C + hq * CHD) * NUM_N + n;
  #pragma unroll
  for (int cq = 0; cq < CHD; cq++){
    float ax = 0.f, bx = 0.f, ay = 0.f, by = 0.f;
    #pragma unroll
    for (int d = 0; d < CHD; d++){
      float a = A[cq * CHD + d];
      ax += a * vxa[d]; bx += a * vxb[d];
      ay += a * vya[d]; by += a * vyb[d];
    }
    f32x2_t st = {G1 * ax + G2 * ay, G1 * bx + G2 * by};
    *(f32x2_t*)(ob + (size_t)cq * NUM_N) = st;
  }
}

// ---------------------------------------------------------------------------
extern "C" void kernel_launch(void* const* d_in, const int* in_sizes, int n_in,
                              void* d_out, int out_size, void* d_ws, size_t ws_size,
                              hipStream_t stream)
{
  const float* x = (const float*)d_in[0];
  const float* y = (const float*)d_in[1];
  const float* conv_w[3] = {(const float*)d_in[2], (const float*)d_in[6], (const float*)d_in[10]};
  const float* conv_b[3] = {(const float*)d_in[3], (const float*)d_in[7], (const float*)d_in[11]};
  const float* dw_w[3]   = {(const float*)d_in[4], (const float*)d_in[8], (const float*)d_in[12]};
  const float* dw_b[3]   = {(const float*)d_in[5], (const float*)d_in[9], (const float*)d_in[13]};
  const float* temp = (const float*)d_in[14];
  const float* g1 = (const float*)d_in[15];
  const float* g2 = (const float*)d_in[16];
  float* out = (float*)d_out;

  // Workspace layout (requires ~202 MB):
  //   z    : [4][384][16384] bf16 (per-branch, reused)      50,331,648 B
  //   qkv  : [3][4][384][16384] bf16                       150,994,944 B
  //   dots1, dots2 : [4][8][24][24] f32                      2x 73,728 B
  //   norms: [4][8][4][24] f32                                  12,288 B
  //   attn : [4][8][24][24] f32                                 73,728 B
  char* ws = (char*)d_ws;
  const size_t ZB = (size_t)NUM_B * NUM_C2 * NUM_N * 2;
  unsigned short* z   = (unsigned short*)ws;
  unsigned short* qkv = (unsigned short*)(ws + ZB);
  float* dots1 = (float*)(ws + 4 * ZB);
  float* dots2 = dots1 + NUM_B * NHEADS * CHD * CHD;
  float* norms = dots2 + NUM_B * NHEADS * CHD * CHD;
  float* attn  = norms + NUM_B * NHEADS * 4 * CHD;

  hipMemsetAsync(dots1, 0,
      (size_t)(2 * NUM_B * NHEADS * CHD * CHD + NUM_B * NHEADS * 4 * CHD) * sizeof(float),
      stream);

  dim3 gg(3, 128, NUM_B), bg(256);
  dim3 gd(NUM_H / 16, NUM_C, NUM_B), bd(256);
  for (int br = 0; br < 3; br++){
    const float* iA = (br == 2) ? y : x;
    const float* iB = (br == 0) ? y : nullptr;
    unsigned short* qkv_br = qkv + (size_t)br * NUM_B * NUM_C2 * NUM_N;
    if (br == 0)
      conv1x1_gemm<1><<<gg, bg, 0, stream>>>(iA, iB, conv_w[br], conv_b[br], z);
    else
      conv1x1_gemm<0><<<gg, bg, 0, stream>>>(iA, iB, conv_w[br], conv_b[br], z);
    gconv3_dw<<<gd, bd, 0, stream>>>(z, dw_w[br], dw_b[br], qkv_br);
  }
  dots_kernel<<<dim3(64, NHEADS, NUM_B), 64, 0, stream>>>(qkv, dots1, dots2, norms);
  softmax_kernel<<<dim3(NUM_B * NHEADS), 64, 0, stream>>>(dots1, dots2, norms, temp, attn);
  out_kernel<<<dim3(32, NHEADS, NUM_B), 256, 0, stream>>>(qkv, attn, g1, g2, out);
}

// Round 3
// 305.504 us; speedup vs baseline: 1.1380x; 1.1380x over previous
//
#include <hip/hip_runtime.h>
#include <hip/hip_bf16.h>
#include <stdint.h>

#define NUM_B 4
#define NUM_C 192
#define NUM_C2 384
#define NUM_H 128
#define NUM_W 128
#define NUM_N 16384
#define NHEADS 8
#define CHD 24

typedef float f32x4_t __attribute__((ext_vector_type(4)));
typedef float f32x2_t __attribute__((ext_vector_type(2)));
typedef __bf16 bf16x8_t __attribute__((ext_vector_type(8)));
typedef unsigned short u16x8_t __attribute__((ext_vector_type(8)));

__device__ __forceinline__ float bf2f(unsigned short u){
  union { unsigned int i; float f; } v; v.i = ((unsigned int)u) << 16; return v.f;
}
__device__ __forceinline__ unsigned short f2bf(float f){
  union { float f; unsigned int i; } v; v.f = f;
  unsigned int x = v.i;
  x += 0x7fffu + ((x >> 16) & 1u);   // round-to-nearest-even
  return (unsigned short)(x >> 16);
}
__device__ __forceinline__ unsigned short f2bf_n(float f){
  union { __bf16 h; unsigned short u; } cv; cv.h = (__bf16)f; return cv.u;
}

// ---------------------------------------------------------------------------
// Kernel 0: prepack conv1x1 weights fp32 -> bf16.
// Layout: [ot(3)][s(6)][o(128)][slot(4)][8 bf16]; slot c holds W k-chunk
// (c ^ ((o>>1)&3)).  A-tile staging is then a LINEAR 8KB copy per (ot,s).
// ---------------------------------------------------------------------------
__global__ __launch_bounds__(256) void prepack_w(const float* __restrict__ W,
                                                 unsigned short* __restrict__ out)
{
  int tid = blockIdx.x * 256 + threadIdx.x;
  if (tid >= 9216) return;
  int c = tid & 3;
  int o = (tid >> 2) & 127;
  int s = (tid >> 9) % 6;
  int ot = tid / 3072;
  int sw = c ^ ((o >> 1) & 3);
  const float* src = W + (size_t)(ot * 128 + o) * NUM_C + s * 32 + sw * 8;
  f32x4_t f0 = *(const f32x4_t*)src;
  f32x4_t f1 = *(const f32x4_t*)(src + 4);
  u16x8_t pk;
  pk[0] = f2bf(f0[0]); pk[1] = f2bf(f0[1]); pk[2] = f2bf(f0[2]); pk[3] = f2bf(f0[3]);
  pk[4] = f2bf(f1[0]); pk[5] = f2bf(f1[1]); pk[6] = f2bf(f1[2]); pk[7] = f2bf(f1[3]);
  *(u16x8_t*)(out + (size_t)tid * 8) = pk;
}

// ---------------------------------------------------------------------------
// Kernel 1: conv1x1 as MFMA GEMM, 128(o) x 128(n) tile, BK=32, dbuf LDS.
//  A: prepacked bf16, linear reg-staged copy (2 x dwordx4 + 2 x ds_write_b128).
//  B: f32x4 global loads -> native bf16 cvt -> round-1-proven [n][40] swizzled
//     LDS layout via 16 scalar ds_write_u16 (the 2B transpose).
//  T14: global->reg loads issued before compute, LDS writes after.
// ---------------------------------------------------------------------------
template<int ADD2>
__global__ __launch_bounds__(256, 2) void conv1x1_gemm(
    const float* __restrict__ inA, const float* __restrict__ inB,
    const unsigned short* __restrict__ Wpk, const float* __restrict__ bias,
    unsigned short* __restrict__ zout)
{
  __shared__ unsigned short As[2][4096];      // [o(128)][32], slot-swizzled
  __shared__ unsigned short Bs[2][128 * 40];  // [n(128)][40], chunk-XOR swizzle
  const int t = threadIdx.x;
  const int lane = t & 63;
  const int wv = t >> 6;
  const int wr = wv >> 1, wc = wv & 1;
  const int o0 = blockIdx.x * 128;
  const int n0 = blockIdx.y * 128;
  const int b  = blockIdx.z;

  const float* in0 = inA + (size_t)b * NUM_C * NUM_N;
  const float* in1 = ADD2 ? (inB + (size_t)b * NUM_C * NUM_N) : nullptr;

  f32x4_t acc[4][4];
  const f32x4_t zz = {0.f, 0.f, 0.f, 0.f};
  #pragma unroll
  for (int m = 0; m < 4; m++)
    #pragma unroll
    for (int nf = 0; nf < 4; nf++) acc[m][nf] = zz;

  u16x8_t areg[2];
  f32x4_t breg[4], breg2[4];

  auto loadA = [&](int ks){
    const u16x8_t* gp = (const u16x8_t*)(Wpk + (size_t)(blockIdx.x * 6 + ks) * 4096);
    areg[0] = gp[t];
    areg[1] = gp[t + 256];
  };
  auto writeA = [&](int buf){
    *(u16x8_t*)(&As[buf][(size_t)t * 8]) = areg[0];
    *(u16x8_t*)(&As[buf][(size_t)(t + 256) * 8]) = areg[1];
  };
  auto loadB = [&](int ks){
    const int k0 = ks * 32;
    #pragma unroll
    for (int i = 0; i < 4; i++){
      int idx = t + 256 * i;
      int k = idx >> 5, n4 = idx & 31;
      breg[i] = *(const f32x4_t*)(in0 + (size_t)(k0 + k) * NUM_N + n0 + n4 * 4);
      if (ADD2)
        breg2[i] = *(const f32x4_t*)(in1 + (size_t)(k0 + k) * NUM_N + n0 + n4 * 4);
    }
  };
  auto writeB = [&](int buf){
    #pragma unroll
    for (int i = 0; i < 4; i++){
      int idx = t + 256 * i;
      int k = idx >> 5, n4 = idx & 31;
      int c = k >> 3, kk = k & 7;
      #pragma unroll
      for (int j2 = 0; j2 < 4; j2++){
        int n = n4 * 4 + j2;
        int sw = c ^ ((n >> 3) & 3);
        float v = breg[i][j2];
        if (ADD2) v += breg2[i][j2];
        Bs[buf][n * 40 + sw * 8 + kk] = f2bf_n(v);
      }
    }
  };

  auto compute = [&](int buf){
    const int rsel = lane & 15;
    const int g = lane >> 4;
    bf16x8_t af[4], bfr[4];
    #pragma unroll
    for (int m = 0; m < 4; m++){
      int r = wr * 64 + m * 16 + rsel;
      int sw = g ^ ((r >> 1) & 3);
      af[m] = *(const bf16x8_t*)(&As[buf][r * 32 + sw * 8]);
    }
    #pragma unroll
    for (int nf = 0; nf < 4; nf++){
      int r = wc * 64 + nf * 16 + rsel;
      int sw = g ^ ((r >> 3) & 3);
      bfr[nf] = *(const bf16x8_t*)(&Bs[buf][r * 40 + sw * 8]);
    }
    #pragma unroll
    for (int m = 0; m < 4; m++)
      #pragma unroll
      for (int nf = 0; nf < 4; nf++)
        acc[m][nf] = __builtin_amdgcn_mfma_f32_16x16x32_bf16(af[m], bfr[nf], acc[m][nf], 0, 0, 0);
  };

  loadA(0); loadB(0);
  writeA(0); writeB(0);
  __syncthreads();
  int buf = 0;
  #pragma unroll 1
  for (int ks = 0; ks < 6; ks++){
    if (ks < 5){
      loadA(ks + 1);           // global -> regs, waits land after compute (T14)
      loadB(ks + 1);
    }
    compute(buf);
    if (ks < 5){
      writeA(buf ^ 1);
      writeB(buf ^ 1);
      __syncthreads();
    }
    buf ^= 1;
  }

  const int colb = lane & 15;
  const int rsub = (lane >> 4) * 4;
  #pragma unroll
  for (int m = 0; m < 4; m++){
    #pragma unroll
    for (int nf = 0; nf < 4; nf++){
      int col = n0 + wc * 64 + nf * 16 + colb;
      #pragma unroll
      for (int r = 0; r < 4; r++){
        int o = o0 + wr * 64 + m * 16 + rsub + r;
        float v = acc[m][nf][r] + bias[o];
        zout[((size_t)b * NUM_C2 + o) * NUM_N + col] = f2bf_n(v);
      }
    }
  }
}

// ---------------------------------------------------------------------------
// Kernel 2: grouped 3x3 conv (groups=192, 2-in/2-out each), SAME zero padding.
// ---------------------------------------------------------------------------
__global__ __launch_bounds__(256) void gconv3_dw(
    const unsigned short* __restrict__ z,
    const float* __restrict__ dww, const float* __restrict__ dwb,
    unsigned short* __restrict__ outq)
{
  const int t = threadIdx.x;
  const int wo = t & 15;
  const int hh = t >> 4;
  const int h = blockIdx.x * 16 + hh;
  const int g = blockIdx.y;
  const int b = blockIdx.z;

  float v[2][3][8];
  #pragma unroll
  for (int ic = 0; ic < 2; ic++){
    const unsigned short* src = z + ((size_t)b * NUM_C2 + 2 * g + ic) * NUM_N;
    #pragma unroll
    for (int dy = 0; dy < 3; dy++){
      int row = h + dy - 1;
      if (row >= 0 && row < NUM_H){
        u16x8_t raw = *(const u16x8_t*)(src + row * NUM_W + wo * 8);
        #pragma unroll
        for (int jj = 0; jj < 8; jj++) v[ic][dy][jj] = bf2f(raw[jj]);
      } else {
        #pragma unroll
        for (int jj = 0; jj < 8; jj++) v[ic][dy][jj] = 0.f;
      }
    }
  }
  float lft[2][3], rgt[2][3];
  #pragma unroll
  for (int ic = 0; ic < 2; ic++)
    #pragma unroll
    for (int dy = 0; dy < 3; dy++){
      float l = __shfl_up(v[ic][dy][7], 1u, 64);
      float r = __shfl_down(v[ic][dy][0], 1u, 64);
      lft[ic][dy] = (wo == 0)  ? 0.f : l;
      rgt[ic][dy] = (wo == 15) ? 0.f : r;
    }
  #pragma unroll
  for (int oc2 = 0; oc2 < 2; oc2++){
    const int oc = 2 * g + oc2;
    float wgt[2][9];
    #pragma unroll
    for (int ic = 0; ic < 2; ic++)
      #pragma unroll
      for (int k9 = 0; k9 < 9; k9++)
        wgt[ic][k9] = dww[(size_t)oc * 18 + ic * 9 + k9];
    float bia = dwb[oc];
    u16x8_t st;
    #pragma unroll
    for (int w8 = 0; w8 < 8; w8++){
      float s = bia;
      #pragma unroll
      for (int ic = 0; ic < 2; ic++)
        #pragma unroll
        for (int ky = 0; ky < 3; ky++)
          #pragma unroll
          for (int kx = 0; kx < 3; kx++){
            int wx = w8 + kx - 1;
            float xv = (wx < 0) ? lft[ic][ky] : ((wx > 7) ? rgt[ic][ky] : v[ic][ky][wx]);
            s += wgt[ic][ky * 3 + kx] * xv;
          }
      st[w8] = f2bf(s);
    }
    *(u16x8_t*)(outq + ((size_t)b * NUM_C2 + oc) * NUM_N + h * NUM_W + wo * 8) = st;
  }
}

// ---------------------------------------------------------------------------
// Kernel 3: fused Gram + norms via MFMA (K split over 64 blocks, fp32 atomics)
// ---------------------------------------------------------------------------
__global__ __launch_bounds__(64) void dots_kernel(
    const unsigned short* __restrict__ qkv,
    float* __restrict__ dots1, float* __restrict__ dots2, float* __restrict__ norms)
{
  const int lane = threadIdx.x;
  const int kc = blockIdx.x;
  const int h = blockIdx.y;
  const int b = blockIdx.z;
  const unsigned short* q1 = qkv + ((size_t)(0 * NUM_B + b) * NUM_C2 + h * CHD) * NUM_N;
  const unsigned short* q2 = qkv + ((size_t)(0 * NUM_B + b) * NUM_C2 + NUM_C + h * CHD) * NUM_N;
  const unsigned short* kx = qkv + ((size_t)(1 * NUM_B + b) * NUM_C2 + h * CHD) * NUM_N;
  const unsigned short* ky = qkv + ((size_t)(2 * NUM_B + b) * NUM_C2 + h * CHD) * NUM_N;

  const f32x4_t zz = {0.f, 0.f, 0.f, 0.f};
  f32x4_t d1[2][2], d2[2][2], nrm[4][2];
  #pragma unroll
  for (int i = 0; i < 2; i++)
    #pragma unroll
    for (int j = 0; j < 2; j++){ d1[i][j] = zz; d2[i][j] = zz; }
  #pragma unroll
  for (int tn = 0; tn < 4; tn++){ nrm[tn][0] = zz; nrm[tn][1] = zz; }

  const int row = lane & 15;
  const int kl = (lane >> 4) * 8;
  #pragma unroll 1
  for (int ks = 0; ks < 8; ks++){
    const size_t k0 = (size_t)kc * 256 + ks * 32 + kl;
    bf16x8_t fq1[2], fq2[2], fkx[2], fky[2];
    #pragma unroll
    for (int rg = 0; rg < 2; rg++){
      size_t off = (size_t)(rg * 16 + row) * NUM_N + k0;
      fq1[rg] = *(const bf16x8_t*)(q1 + off);
      fq2[rg] = *(const bf16x8_t*)(q2 + off);
      fkx[rg] = *(const bf16x8_t*)(kx + off);
      fky[rg] = *(const bf16x8_t*)(ky + off);
    }
    #pragma unroll
    for (int i = 0; i < 2; i++)
      #pragma unroll
      for (int j = 0; j < 2; j++){
        d1[i][j] = __builtin_amdgcn_mfma_f32_16x16x32_bf16(fq1[i], fky[j], d1[i][j], 0, 0, 0);
        d2[i][j] = __builtin_amdgcn_mfma_f32_16x16x32_bf16(fq2[i], fkx[j], d2[i][j], 0, 0, 0);
      }
    #pragma unroll
    for (int rg = 0; rg < 2; rg++){
      nrm[0][rg] = __builtin_amdgcn_mfma_f32_16x16x32_bf16(fq1[rg], fq1[rg], nrm[0][rg], 0, 0, 0);
      nrm[1][rg] = __builtin_amdgcn_mfma_f32_16x16x32_bf16(fq2[rg], fq2[rg], nrm[1][rg], 0, 0, 0);
      nrm[2][rg] = __builtin_amdgcn_mfma_f32_16x16x32_bf16(fkx[rg], fkx[rg], nrm[2][rg], 0, 0, 0);
      nrm[3][rg] = __builtin_amdgcn_mfma_f32_16x16x32_bf16(fky[rg], fky[rg], nrm[3][rg], 0, 0, 0);
    }
  }

  float* D1 = dots1 + (size_t)(b * NHEADS + h) * CHD * CHD;
  float* D2 = dots2 + (size_t)(b * NHEADS + h) * CHD * CHD;
  float* NB = norms + (size_t)(b * NHEADS + h) * 4 * CHD;
  const int colb = lane & 15;
  const int rb = (lane >> 4) * 4;
  #pragma unroll
  for (int i = 0; i < 2; i++)
    #pragma unroll
    for (int j = 0; j < 2; j++){
      int cc = j * 16 + colb;
      if (cc < CHD){
        #pragma unroll
        for (int r = 0; r < 4; r++){
          int rr = i * 16 + rb + r;
          if (rr < CHD){
            atomicAdd(&D1[rr * CHD + cc], d1[i][j][r]);
            atomicAdd(&D2[rr * CHD + cc], d2[i][j][r]);
          }
        }
      }
    }
  #pragma unroll
  for (int tn = 0; tn < 4; tn++)
    #pragma unroll
    for (int rg = 0; rg < 2; rg++){
      int cc = rg * 16 + colb;
      #pragma unroll
      for (int r = 0; r < 4; r++){
        int rr = rg * 16 + rb + r;
        if (rr == cc && rr < CHD) atomicAdd(&NB[tn * CHD + rr], nrm[tn][rg][r]);
      }
    }
}

// ---------------------------------------------------------------------------
// Kernel 4: cosine-normalize, temperature, softmax -> attn (4,8,24,24) fp32
// ---------------------------------------------------------------------------
__global__ __launch_bounds__(64) void softmax_kernel(
    const float* __restrict__ dots1, const float* __restrict__ dots2,
    const float* __restrict__ norms, const float* __restrict__ temp,
    float* __restrict__ attn)
{
  const int c = threadIdx.x;
  const int bh = blockIdx.x;
  if (c >= CHD) return;
  const int h = bh & 7;
  const float* D1 = dots1 + (size_t)bh * CHD * CHD;
  const float* D2 = dots2 + (size_t)bh * CHD * CHD;
  const float* NB = norms + (size_t)bh * 4 * CHD;
  float n1 = fmaxf(sqrtf(NB[0 * CHD + c]), 1e-12f);
  float n2 = fmaxf(sqrtf(NB[1 * CHD + c]), 1e-12f);
  float T = temp[h];
  float l[CHD];
  float m = -1e30f;
  #pragma unroll
  for (int d = 0; d < CHD; d++){
    float nx = fmaxf(sqrtf(NB[2 * CHD + d]), 1e-12f);
    float ny = fmaxf(sqrtf(NB[3 * CHD + d]), 1e-12f);
    float e = (D1[c * CHD + d] / (n1 * ny) + D2[c * CHD + d] / (n2 * nx)) * T;
    l[d] = e; m = fmaxf(m, e);
  }
  float s = 0.f;
  #pragma unroll
  for (int d = 0; d < CHD; d++){ float p = expf(l[d] - m); l[d] = p; s += p; }
  float inv = 1.f / s;
  float* A = attn + (size_t)bh * CHD * CHD + c * CHD;
  #pragma unroll
  for (int d = 0; d < CHD; d++) A[d] = l[d] * inv;
}

// ---------------------------------------------------------------------------
// Kernel 5: out = gamma1*attn@vx + gamma2*attn@vy
// ---------------------------------------------------------------------------
__global__ __launch_bounds__(256) void out_kernel(
    const unsigned short* __restrict__ qkv, const float* __restrict__ attn,
    const float* __restrict__ g1, const float* __restrict__ g2,
    float* __restrict__ out)
{
  __shared__ float A[CHD * CHD];
  const int t = threadIdx.x;
  const int nc = blockIdx.x, hq = blockIdx.y, b = blockIdx.z;
  const float* Ag = attn + (size_t)(b * NHEADS + hq) * CHD * CHD;
  for (int i = t; i < CHD * CHD; i += 256) A[i] = Ag[i];
  __syncthreads();
  const int n = nc * 512 + t * 2;
  const unsigned short* vx = qkv + ((size_t)(1 * NUM_B + b) * NUM_C2 + NUM_C + hq * CHD) * NUM_N + n;
  const unsigned short* vy = qkv + ((size_t)(2 * NUM_B + b) * NUM_C2 + NUM_C + hq * CHD) * NUM_N + n;
  float vxa[CHD], vxb[CHD], vya[CHD], vyb[CHD];
  #pragma unroll
  for (int d = 0; d < CHD; d++){
    unsigned int rx = *(const unsigned int*)(vx + (size_t)d * NUM_N);
    unsigned int ry = *(const unsigned int*)(vy + (size_t)d * NUM_N);
    vxa[d] = bf2f((unsigned short)(rx & 0xffffu));
    vxb[d] = bf2f((unsigned short)(rx >> 16));
    vya[d] = bf2f((unsigned short)(ry & 0xffffu));
    vyb[d] = bf2f((unsigned short)(ry >> 16));
  }
  const float G1 = g1[0], G2 = g2[0];
  float* ob = out + ((size_t)b * NUM_C + hq * CHD) * NUM_N + n;
  #pragma unroll
  for (int cq = 0; cq < CHD; cq++){
    float ax = 0.f, bx = 0.f, ay = 0.f, by = 0.f;
    #pragma unroll
    for (int d = 0; d < CHD; d++){
      float a = A[cq * CHD + d];
      ax += a * vxa[d]; bx += a * vxb[d];
      ay += a * vya[d]; by += a * vyb[d];
    }
    f32x2_t st = {G1 * ax + G2 * ay, G1 * bx + G2 * by};
    *(f32x2_t*)(ob + (size_t)cq * NUM_N) = st;
  }
}

// ---------------------------------------------------------------------------
extern "C" void kernel_launch(void* const* d_in, const int* in_sizes, int n_in,
                              void* d_out, int out_size, void* d_ws, size_t ws_size,
                              hipStream_t stream)
{
  const float* x = (const float*)d_in[0];
  const float* y = (const float*)d_in[1];
  const float* conv_w[3] = {(const float*)d_in[2], (const float*)d_in[6], (const float*)d_in[10]};
  const float* conv_b[3] = {(const float*)d_in[3], (const float*)d_in[7], (const float*)d_in[11]};
  const float* dw_w[3]   = {(const float*)d_in[4], (const float*)d_in[8], (const float*)d_in[12]};
  const float* dw_b[3]   = {(const float*)d_in[5], (const float*)d_in[9], (const float*)d_in[13]};
  const float* temp = (const float*)d_in[14];
  const float* g1 = (const float*)d_in[15];
  const float* g2 = (const float*)d_in[16];
  float* out = (float*)d_out;

  // Workspace layout (~202.1 MB):
  //   z    : [4][384][16384] bf16                           50,331,648 B
  //   qkv  : [3][4][384][16384] bf16                       150,994,944 B
  //   dots1/dots2/norms/attn : small f32
  //   Wpk  : [3][9216][8] bf16 prepacked weights               442,368 B
  char* ws = (char*)d_ws;
  const size_t ZB = (size_t)NUM_B * NUM_C2 * NUM_N * 2;
  unsigned short* z   = (unsigned short*)ws;
  unsigned short* qkv = (unsigned short*)(ws + ZB);
  float* dots1 = (float*)(ws + 4 * ZB);
  float* dots2 = dots1 + NUM_B * NHEADS * CHD * CHD;
  float* norms = dots2 + NUM_B * NHEADS * CHD * CHD;
  float* attn  = norms + NUM_B * NHEADS * 4 * CHD;
  unsigned short* Wpk = (unsigned short*)(attn + NUM_B * NHEADS * CHD * CHD);

  hipMemsetAsync(dots1, 0,
      (size_t)(2 * NUM_B * NHEADS * CHD * CHD + NUM_B * NHEADS * 4 * CHD) * sizeof(float),
      stream);
  for (int br = 0; br < 3; br++)
    prepack_w<<<36, 256, 0, stream>>>(conv_w[br], Wpk + (size_t)br * 73728);

  dim3 gg(3, 128, NUM_B), bg(256);
  dim3 gd(NUM_H / 16, NUM_C, NUM_B), bd(256);
  for (int br = 0; br < 3; br++){
    const float* iA = (br == 2) ? y : x;
    const float* iB = (br == 0) ? y : nullptr;
    unsigned short* qkv_br = qkv + (size_t)br * NUM_B * NUM_C2 * NUM_N;
    if (br == 0)
      conv1x1_gemm<1><<<gg, bg, 0, stream>>>(iA, iB, Wpk + 0 * 73728, conv_b[br], z);
    else
      conv1x1_gemm<0><<<gg, bg, 0, stream>>>(iA, nullptr, Wpk + (size_t)br * 73728, conv_b[br], z);
    gconv3_dw<<<gd, bd, 0, stream>>>(z, dw_w[br], dw_b[br], qkv_br);
  }
  dots_kernel<<<dim3(64, NHEADS, NUM_B), 64, 0, stream>>>(qkv, dots1, dots2, norms);
  softmax_kernel<<<dim3(NUM_B * NHEADS), 64, 0, stream>>>(dots1, dots2, norms, temp, attn);
  out_kernel<<<dim3(32, NHEADS, NUM_B), 256, 0, stream>>>(qkv, attn, g1, g2, out);
}

// Round 4
// 289.376 us; speedup vs baseline: 1.2014x; 1.0557x over previous
//
#include <hip/hip_runtime.h>
#include <hip/hip_bf16.h>
#include <stdint.h>

#define NUM_B 4
#define NUM_C 192
#define NUM_C2 384
#define NUM_H 128
#define NUM_W 128
#define NUM_N 16384
#define NHEADS 8
#define CHD 24

typedef float f32x4_t __attribute__((ext_vector_type(4)));
typedef float f32x2_t __attribute__((ext_vector_type(2)));
typedef __bf16 bf16x8_t __attribute__((ext_vector_type(8)));
typedef unsigned short u16x8_t __attribute__((ext_vector_type(8)));

__device__ __forceinline__ float bf2f(unsigned short u){
  union { unsigned int i; float f; } v; v.i = ((unsigned int)u) << 16; return v.f;
}
__device__ __forceinline__ unsigned short f2bf(float f){
  union { float f; unsigned int i; } v; v.f = f;
  unsigned int x = v.i;
  x += 0x7fffu + ((x >> 16) & 1u);   // round-to-nearest-even
  return (unsigned short)(x >> 16);
}
__device__ __forceinline__ unsigned short f2bf_n(float f){
  union { __bf16 h; unsigned short u; } cv; cv.h = (__bf16)f; return cv.u;
}

// ---------------------------------------------------------------------------
// Kernel 0a: prepack conv1x1 weights fp32 -> bf16.
// Layout: [ot(3)][s(6)][o(128)][slot(4)][8 bf16]; slot c holds W k-chunk
// (c ^ ((o>>1)&3)).  A-tile staging is then a LINEAR 8KB copy per (ot,s).
// ---------------------------------------------------------------------------
__global__ __launch_bounds__(256) void prepack_w(const float* __restrict__ W,
                                                 unsigned short* __restrict__ out)
{
  int tid = blockIdx.x * 256 + threadIdx.x;
  if (tid >= 9216) return;
  int c = tid & 3;
  int o = (tid >> 2) & 127;
  int s = (tid >> 9) % 6;
  int ot = tid / 3072;
  int sw = c ^ ((o >> 1) & 3);
  const float* src = W + (size_t)(ot * 128 + o) * NUM_C + s * 32 + sw * 8;
  f32x4_t f0 = *(const f32x4_t*)src;
  f32x4_t f1 = *(const f32x4_t*)(src + 4);
  u16x8_t pk;
  pk[0] = f2bf(f0[0]); pk[1] = f2bf(f0[1]); pk[2] = f2bf(f0[2]); pk[3] = f2bf(f0[3]);
  pk[4] = f2bf(f1[0]); pk[5] = f2bf(f1[1]); pk[6] = f2bf(f1[2]); pk[7] = f2bf(f1[3]);
  *(u16x8_t*)(out + (size_t)tid * 8) = pk;
}

// ---------------------------------------------------------------------------
// Kernel 0b: prepack inputs x,y fp32 -> bf16 in the SAME tiled/baked layout as
// the weights: [b][nt(128)][s(6)][n(128)][slot(4)][8], slot c holds k-chunk
// (c ^ ((n>>1)&3)).  Conv B-staging becomes a LINEAR 8KB copy per (b,nt,s).
// One streaming pass: read x,y f32 coalesced, transpose via LDS, flush 16B.
// ---------------------------------------------------------------------------
__global__ __launch_bounds__(256) void prepack_in(
    const float* __restrict__ x, const float* __restrict__ y,
    unsigned short* __restrict__ xb, unsigned short* __restrict__ yb)
{
  __shared__ __align__(16) unsigned short LX[4096];
  __shared__ __align__(16) unsigned short LY[4096];
  const int t = threadIdx.x;
  const int nt = blockIdx.x, s = blockIdx.y, b = blockIdx.z;
  const float* px = x + (size_t)b * NUM_C * NUM_N + (size_t)s * 32 * NUM_N + nt * 128;
  const float* py = y + (size_t)b * NUM_C * NUM_N + (size_t)s * 32 * NUM_N + nt * 128;
  #pragma unroll
  for (int i = 0; i < 4; i++){
    int idx = t + 256 * i;
    int k = idx >> 5, n4 = idx & 31;
    f32x4_t vx4 = *(const f32x4_t*)(px + (size_t)k * NUM_N + n4 * 4);
    f32x4_t vy4 = *(const f32x4_t*)(py + (size_t)k * NUM_N + n4 * 4);
    int kc = k >> 3, kk = k & 7;
    #pragma unroll
    for (int j2 = 0; j2 < 4; j2++){
      int n = n4 * 4 + j2;
      int slot = kc ^ ((n >> 1) & 3);
      LX[n * 32 + slot * 8 + kk] = f2bf_n(vx4[j2]);
      LY[n * 32 + slot * 8 + kk] = f2bf_n(vy4[j2]);
    }
  }
  __syncthreads();
  size_t obase = ((size_t)(b * 128 + nt) * 6 + s) * 4096;
  *(u16x8_t*)(xb + obase + (size_t)t * 8)         = *(const u16x8_t*)&LX[t * 8];
  *(u16x8_t*)(xb + obase + (size_t)(t + 256) * 8) = *(const u16x8_t*)&LX[(t + 256) * 8];
  *(u16x8_t*)(yb + obase + (size_t)t * 8)         = *(const u16x8_t*)&LY[t * 8];
  *(u16x8_t*)(yb + obase + (size_t)(t + 256) * 8) = *(const u16x8_t*)&LY[(t + 256) * 8];
}

// ---------------------------------------------------------------------------
// Kernel 1: conv1x1 as MFMA GEMM, 128(o) x 128(n) tile, BK=32, dbuf LDS.
// Both A and B prepacked bf16 -> staging is 4 x 16B load + 4 x ds_write_b128
// linear (proven R3 A-path structure).  T14: loads before compute, writes
// after, one barrier per K-step.  br0 adds xb+yb during writeB.
// ---------------------------------------------------------------------------
template<int ADD2>
__global__ __launch_bounds__(256, 4) void conv1x1_gemm(
    const unsigned short* __restrict__ Bpk0, const unsigned short* __restrict__ Bpk1,
    const unsigned short* __restrict__ Wpk, const float* __restrict__ bias,
    unsigned short* __restrict__ zout)
{
  __shared__ __align__(16) unsigned short As[2][4096];  // [o(128)][slot(4)][8]
  __shared__ __align__(16) unsigned short Bs[2][4096];  // [n(128)][slot(4)][8]
  const int t = threadIdx.x;
  const int lane = t & 63;
  const int wv = t >> 6;
  const int wr = wv >> 1, wc = wv & 1;
  const int o0 = blockIdx.x * 128;
  const int n0 = blockIdx.y * 128;
  const int b  = blockIdx.z;

  f32x4_t acc[4][4];
  const f32x4_t zz = {0.f, 0.f, 0.f, 0.f};
  #pragma unroll
  for (int m = 0; m < 4; m++)
    #pragma unroll
    for (int nf = 0; nf < 4; nf++) acc[m][nf] = zz;

  u16x8_t areg[2], breg[2], breg2[2];

  auto loadA = [&](int ks){
    const u16x8_t* gp = (const u16x8_t*)(Wpk + (size_t)(blockIdx.x * 6 + ks) * 4096);
    areg[0] = gp[t];
    areg[1] = gp[t + 256];
  };
  auto loadB = [&](int ks){
    size_t off = ((size_t)(b * 128 + blockIdx.y) * 6 + ks) * 4096;
    const u16x8_t* gp = (const u16x8_t*)(Bpk0 + off);
    breg[0] = gp[t];
    breg[1] = gp[t + 256];
    if (ADD2){
      const u16x8_t* gp2 = (const u16x8_t*)(Bpk1 + off);
      breg2[0] = gp2[t];
      breg2[1] = gp2[t + 256];
    }
  };
  auto writeA = [&](int buf){
    *(u16x8_t*)(&As[buf][(size_t)t * 8]) = areg[0];
    *(u16x8_t*)(&As[buf][(size_t)(t + 256) * 8]) = areg[1];
  };
  auto writeB = [&](int buf){
    if (!ADD2){
      *(u16x8_t*)(&Bs[buf][(size_t)t * 8]) = breg[0];
      *(u16x8_t*)(&Bs[buf][(size_t)(t + 256) * 8]) = breg[1];
    } else {
      #pragma unroll
      for (int i = 0; i < 2; i++){
        u16x8_t r;
        #pragma unroll
        for (int j = 0; j < 8; j++)
          r[j] = f2bf_n(bf2f(breg[i][j]) + bf2f(breg2[i][j]));
        *(u16x8_t*)(&Bs[buf][(size_t)(t + 256 * i) * 8]) = r;
      }
    }
  };

  auto compute = [&](int buf){
    const int rsel = lane & 15;
    const int g = lane >> 4;
    bf16x8_t af[4], bfr[4];
    #pragma unroll
    for (int m = 0; m < 4; m++){
      int r = wr * 64 + m * 16 + rsel;
      int sw = g ^ ((r >> 1) & 3);
      af[m] = *(const bf16x8_t*)(&As[buf][r * 32 + sw * 8]);
    }
    #pragma unroll
    for (int nf = 0; nf < 4; nf++){
      int r = wc * 64 + nf * 16 + rsel;
      int sw = g ^ ((r >> 1) & 3);
      bfr[nf] = *(const bf16x8_t*)(&Bs[buf][r * 32 + sw * 8]);
    }
    #pragma unroll
    for (int m = 0; m < 4; m++)
      #pragma unroll
      for (int nf = 0; nf < 4; nf++)
        acc[m][nf] = __builtin_amdgcn_mfma_f32_16x16x32_bf16(af[m], bfr[nf], acc[m][nf], 0, 0, 0);
  };

  loadA(0); loadB(0);
  writeA(0); writeB(0);
  __syncthreads();
  int buf = 0;
  #pragma unroll 1
  for (int ks = 0; ks < 6; ks++){
    if (ks < 5){
      loadA(ks + 1);           // global -> regs; vmcnt waits land after compute
      loadB(ks + 1);
    }
    compute(buf);
    if (ks < 5){
      writeA(buf ^ 1);
      writeB(buf ^ 1);
      __syncthreads();
    }
    buf ^= 1;
  }

  const int colb = lane & 15;
  const int rsub = (lane >> 4) * 4;
  #pragma unroll
  for (int m = 0; m < 4; m++){
    #pragma unroll
    for (int nf = 0; nf < 4; nf++){
      int col = n0 + wc * 64 + nf * 16 + colb;
      #pragma unroll
      for (int r = 0; r < 4; r++){
        int o = o0 + wr * 64 + m * 16 + rsub + r;
        float v = acc[m][nf][r] + bias[o];
        zout[((size_t)b * NUM_C2 + o) * NUM_N + col] = f2bf_n(v);
      }
    }
  }
}

// ---------------------------------------------------------------------------
// Kernel 2: grouped 3x3 conv (groups=192, 2-in/2-out each), SAME zero padding.
// ---------------------------------------------------------------------------
__global__ __launch_bounds__(256) void gconv3_dw(
    const unsigned short* __restrict__ z,
    const float* __restrict__ dww, const float* __restrict__ dwb,
    unsigned short* __restrict__ outq)
{
  const int t = threadIdx.x;
  const int wo = t & 15;
  const int hh = t >> 4;
  const int h = blockIdx.x * 16 + hh;
  const int g = blockIdx.y;
  const int b = blockIdx.z;

  float v[2][3][8];
  #pragma unroll
  for (int ic = 0; ic < 2; ic++){
    const unsigned short* src = z + ((size_t)b * NUM_C2 + 2 * g + ic) * NUM_N;
    #pragma unroll
    for (int dy = 0; dy < 3; dy++){
      int row = h + dy - 1;
      if (row >= 0 && row < NUM_H){
        u16x8_t raw = *(const u16x8_t*)(src + row * NUM_W + wo * 8);
        #pragma unroll
        for (int jj = 0; jj < 8; jj++) v[ic][dy][jj] = bf2f(raw[jj]);
      } else {
        #pragma unroll
        for (int jj = 0; jj < 8; jj++) v[ic][dy][jj] = 0.f;
      }
    }
  }
  float lft[2][3], rgt[2][3];
  #pragma unroll
  for (int ic = 0; ic < 2; ic++)
    #pragma unroll
    for (int dy = 0; dy < 3; dy++){
      float l = __shfl_up(v[ic][dy][7], 1u, 64);
      float r = __shfl_down(v[ic][dy][0], 1u, 64);
      lft[ic][dy] = (wo == 0)  ? 0.f : l;
      rgt[ic][dy] = (wo == 15) ? 0.f : r;
    }
  #pragma unroll
  for (int oc2 = 0; oc2 < 2; oc2++){
    const int oc = 2 * g + oc2;
    float wgt[2][9];
    #pragma unroll
    for (int ic = 0; ic < 2; ic++)
      #pragma unroll
      for (int k9 = 0; k9 < 9; k9++)
        wgt[ic][k9] = dww[(size_t)oc * 18 + ic * 9 + k9];
    float bia = dwb[oc];
    u16x8_t st;
    #pragma unroll
    for (int w8 = 0; w8 < 8; w8++){
      float s = bia;
      #pragma unroll
      for (int ic = 0; ic < 2; ic++)
        #pragma unroll
        for (int ky = 0; ky < 3; ky++)
          #pragma unroll
          for (int kx = 0; kx < 3; kx++){
            int wx = w8 + kx - 1;
            float xv = (wx < 0) ? lft[ic][ky] : ((wx > 7) ? rgt[ic][ky] : v[ic][ky][wx]);
            s += wgt[ic][ky * 3 + kx] * xv;
          }
      st[w8] = f2bf(s);
    }
    *(u16x8_t*)(outq + ((size_t)b * NUM_C2 + oc) * NUM_N + h * NUM_W + wo * 8) = st;
  }
}

// ---------------------------------------------------------------------------
// Kernel 3: fused Gram + norms via MFMA (K split over 64 blocks, fp32 atomics).
// Full unroll lets the compiler software-pipeline loads across the 8 K-steps;
// garbage rows 24..31 clamped to 23 (duplicate addrs coalesce, 25% fetch cut).
// ---------------------------------------------------------------------------
__global__ __launch_bounds__(64) void dots_kernel(
    const unsigned short* __restrict__ qkv0, const unsigned short* __restrict__ qkv1,
    const unsigned short* __restrict__ qkv2,
    float* __restrict__ dots1, float* __restrict__ dots2, float* __restrict__ norms)
{
  const int lane = threadIdx.x;
  const int kc = blockIdx.x;
  const int h = blockIdx.y;
  const int b = blockIdx.z;
  const unsigned short* q1 = qkv0 + ((size_t)b * NUM_C2 + h * CHD) * NUM_N;
  const unsigned short* q2 = qkv0 + ((size_t)b * NUM_C2 + NUM_C + h * CHD) * NUM_N;
  const unsigned short* kx = qkv1 + ((size_t)b * NUM_C2 + h * CHD) * NUM_N;
  const unsigned short* ky = qkv2 + ((size_t)b * NUM_C2 + h * CHD) * NUM_N;

  const f32x4_t zz = {0.f, 0.f, 0.f, 0.f};
  f32x4_t d1[2][2], d2[2][2], nrm[4][2];
  #pragma unroll
  for (int i = 0; i < 2; i++)
    #pragma unroll
    for (int j = 0; j < 2; j++){ d1[i][j] = zz; d2[i][j] = zz; }
  #pragma unroll
  for (int tn = 0; tn < 4; tn++){ nrm[tn][0] = zz; nrm[tn][1] = zz; }

  const int row = lane & 15;
  const int kl = (lane >> 4) * 8;
  const int r0 = row;
  const int r1 = (16 + row < CHD) ? (16 + row) : (CHD - 1);   // clamp garbage rows
  #pragma unroll
  for (int ks = 0; ks < 8; ks++){
    const size_t k0 = (size_t)kc * 256 + ks * 32 + kl;
    const size_t off0 = (size_t)r0 * NUM_N + k0;
    const size_t off1 = (size_t)r1 * NUM_N + k0;
    bf16x8_t fq1[2], fq2[2], fkx[2], fky[2];
    fq1[0] = *(const bf16x8_t*)(q1 + off0);  fq1[1] = *(const bf16x8_t*)(q1 + off1);
    fq2[0] = *(const bf16x8_t*)(q2 + off0);  fq2[1] = *(const bf16x8_t*)(q2 + off1);
    fkx[0] = *(const bf16x8_t*)(kx + off0);  fkx[1] = *(const bf16x8_t*)(kx + off1);
    fky[0] = *(const bf16x8_t*)(ky + off0);  fky[1] = *(const bf16x8_t*)(ky + off1);
    #pragma unroll
    for (int i = 0; i < 2; i++)
      #pragma unroll
      for (int j = 0; j < 2; j++){
        d1[i][j] = __builtin_amdgcn_mfma_f32_16x16x32_bf16(fq1[i], fky[j], d1[i][j], 0, 0, 0);
        d2[i][j] = __builtin_amdgcn_mfma_f32_16x16x32_bf16(fq2[i], fkx[j], d2[i][j], 0, 0, 0);
      }
    #pragma unroll
    for (int rg = 0; rg < 2; rg++){
      nrm[0][rg] = __builtin_amdgcn_mfma_f32_16x16x32_bf16(fq1[rg], fq1[rg], nrm[0][rg], 0, 0, 0);
      nrm[1][rg] = __builtin_amdgcn_mfma_f32_16x16x32_bf16(fq2[rg], fq2[rg], nrm[1][rg], 0, 0, 0);
      nrm[2][rg] = __builtin_amdgcn_mfma_f32_16x16x32_bf16(fkx[rg], fkx[rg], nrm[2][rg], 0, 0, 0);
      nrm[3][rg] = __builtin_amdgcn_mfma_f32_16x16x32_bf16(fky[rg], fky[rg], nrm[3][rg], 0, 0, 0);
    }
  }

  float* D1 = dots1 + (size_t)(b * NHEADS + h) * CHD * CHD;
  float* D2 = dots2 + (size_t)(b * NHEADS + h) * CHD * CHD;
  float* NB = norms + (size_t)(b * NHEADS + h) * 4 * CHD;
  const int colb = lane & 15;
  const int rb = (lane >> 4) * 4;
  #pragma unroll
  for (int i = 0; i < 2; i++)
    #pragma unroll
    for (int j = 0; j < 2; j++){
      int cc = j * 16 + colb;
      if (cc < CHD){
        #pragma unroll
        for (int r = 0; r < 4; r++){
          int rr = i * 16 + rb + r;
          if (rr < CHD){
            atomicAdd(&D1[rr * CHD + cc], d1[i][j][r]);
            atomicAdd(&D2[rr * CHD + cc], d2[i][j][r]);
          }
        }
      }
    }
  #pragma unroll
  for (int tn = 0; tn < 4; tn++)
    #pragma unroll
    for (int rg = 0; rg < 2; rg++){
      int cc = rg * 16 + colb;
      #pragma unroll
      for (int r = 0; r < 4; r++){
        int rr = rg * 16 + rb + r;
        if (rr == cc && rr < CHD) atomicAdd(&NB[tn * CHD + rr], nrm[tn][rg][r]);
      }
    }
}

// ---------------------------------------------------------------------------
// Kernel 4: cosine-normalize, temperature, softmax -> attn (4,8,24,24) fp32
// ---------------------------------------------------------------------------
__global__ __launch_bounds__(64) void softmax_kernel(
    const float* __restrict__ dots1, const float* __restrict__ dots2,
    const float* __restrict__ norms, const float* __restrict__ temp,
    float* __restrict__ attn)
{
  const int c = threadIdx.x;
  const int bh = blockIdx.x;
  if (c >= CHD) return;
  const int h = bh & 7;
  const float* D1 = dots1 + (size_t)bh * CHD * CHD;
  const float* D2 = dots2 + (size_t)bh * CHD * CHD;
  const float* NB = norms + (size_t)bh * 4 * CHD;
  float n1 = fmaxf(sqrtf(NB[0 * CHD + c]), 1e-12f);
  float n2 = fmaxf(sqrtf(NB[1 * CHD + c]), 1e-12f);
  float T = temp[h];
  float l[CHD];
  float m = -1e30f;
  #pragma unroll
  for (int d = 0; d < CHD; d++){
    float nx = fmaxf(sqrtf(NB[2 * CHD + d]), 1e-12f);
    float ny = fmaxf(sqrtf(NB[3 * CHD + d]), 1e-12f);
    float e = (D1[c * CHD + d] / (n1 * ny) + D2[c * CHD + d] / (n2 * nx)) * T;
    l[d] = e; m = fmaxf(m, e);
  }
  float s = 0.f;
  #pragma unroll
  for (int d = 0; d < CHD; d++){ float p = expf(l[d] - m); l[d] = p; s += p; }
  float inv = 1.f / s;
  float* A = attn + (size_t)bh * CHD * CHD + c * CHD;
  #pragma unroll
  for (int d = 0; d < CHD; d++) A[d] = l[d] * inv;
}

// ---------------------------------------------------------------------------
// Kernel 5: out = gamma1*attn@vx + gamma2*attn@vy
// ---------------------------------------------------------------------------
__global__ __launch_bounds__(256) void out_kernel(
    const unsigned short* __restrict__ qkv1, const unsigned short* __restrict__ qkv2,
    const float* __restrict__ attn,
    const float* __restrict__ g1, const float* __restrict__ g2,
    float* __restrict__ out)
{
  __shared__ float A[CHD * CHD];
  const int t = threadIdx.x;
  const int nc = blockIdx.x, hq = blockIdx.y, b = blockIdx.z;
  const float* Ag = attn + (size_t)(b * NHEADS + hq) * CHD * CHD;
  for (int i = t; i < CHD * CHD; i += 256) A[i] = Ag[i];
  __syncthreads();
  const int n = nc * 512 + t * 2;
  const unsigned short* vx = qkv1 + ((size_t)b * NUM_C2 + NUM_C + hq * CHD) * NUM_N + n;
  const unsigned short* vy = qkv2 + ((size_t)b * NUM_C2 + NUM_C + hq * CHD) * NUM_N + n;
  float vxa[CHD], vxb[CHD], vya[CHD], vyb[CHD];
  #pragma unroll
  for (int d = 0; d < CHD; d++){
    unsigned int rx = *(const unsigned int*)(vx + (size_t)d * NUM_N);
    unsigned int ry = *(const unsigned int*)(vy + (size_t)d * NUM_N);
    vxa[d] = bf2f((unsigned short)(rx & 0xffffu));
    vxb[d] = bf2f((unsigned short)(rx >> 16));
    vya[d] = bf2f((unsigned short)(ry & 0xffffu));
    vyb[d] = bf2f((unsigned short)(ry >> 16));
  }
  const float G1 = g1[0], G2 = g2[0];
  float* ob = out + ((size_t)b * NUM_C + hq * CHD) * NUM_N + n;
  #pragma unroll
  for (int cq = 0; cq < CHD; cq++){
    float ax = 0.f, bx = 0.f, ay = 0.f, by = 0.f;
    #pragma unroll
    for (int d = 0; d < CHD; d++){
      float a = A[cq * CHD + d];
      ax += a * vxa[d]; bx += a * vxb[d];
      ay += a * vya[d]; by += a * vyb[d];
    }
    f32x2_t st = {G1 * ax + G2 * ay, G1 * bx + G2 * by};
    *(f32x2_t*)(ob + (size_t)cq * NUM_N) = st;
  }
}

// ---------------------------------------------------------------------------
extern "C" void kernel_launch(void* const* d_in, const int* in_sizes, int n_in,
                              void* d_out, int out_size, void* d_ws, size_t ws_size,
                              hipStream_t stream)
{
  const float* x = (const float*)d_in[0];
  const float* y = (const float*)d_in[1];
  const float* conv_b[3] = {(const float*)d_in[3], (const float*)d_in[7], (const float*)d_in[11]};
  const float* dw_w[3]   = {(const float*)d_in[4], (const float*)d_in[8], (const float*)d_in[12]};
  const float* dw_b[3]   = {(const float*)d_in[5], (const float*)d_in[9], (const float*)d_in[13]};
  const float* conv_w[3] = {(const float*)d_in[2], (const float*)d_in[6], (const float*)d_in[10]};
  const float* temp = (const float*)d_in[14];
  const float* g1 = (const float*)d_in[15];
  const float* g2 = (const float*)d_in[16];
  float* out = (float*)d_out;

  // Workspace layout (~202.0 MB), with aliasing:
  //   [0,           25165824)  xb  (prepacked bf16 x)   -- later qkv_br0 low
  //   [25165824,    50331648)  yb  (prepacked bf16 y)   -- later qkv_br0 high
  //   [50331648,   100663296)  z   (conv output, reused per branch)
  //   [100663296,  150994944)  qkv_br1
  //   [150994944,  201326592)  qkv_br2
  //   [201326592, ...        )  dots1/dots2/norms/attn/Wpk (small)
  // Branch order c1,g1,c2,g2,c0,g0 makes xb/yb dead exactly when gconv0
  // writes qkv_br0 over them (stream-ordered).
  char* ws = (char*)d_ws;
  unsigned short* xb   = (unsigned short*)ws;
  unsigned short* yb   = (unsigned short*)(ws + 25165824);
  unsigned short* qkv0 = (unsigned short*)ws;
  unsigned short* z    = (unsigned short*)(ws + 50331648);
  unsigned short* qkv1 = (unsigned short*)(ws + 100663296);
  unsigned short* qkv2 = (unsigned short*)(ws + 150994944);
  float* dots1 = (float*)(ws + 201326592);
  float* dots2 = dots1 + NUM_B * NHEADS * CHD * CHD;
  float* norms = dots2 + NUM_B * NHEADS * CHD * CHD;
  float* attn  = norms + NUM_B * NHEADS * 4 * CHD;
  unsigned short* Wpk = (unsigned short*)(attn + NUM_B * NHEADS * CHD * CHD);

  hipMemsetAsync(dots1, 0,
      (size_t)(2 * NUM_B * NHEADS * CHD * CHD + NUM_B * NHEADS * 4 * CHD) * sizeof(float),
      stream);
  for (int br = 0; br < 3; br++)
    prepack_w<<<36, 256, 0, stream>>>(conv_w[br], Wpk + (size_t)br * 73728);
  prepack_in<<<dim3(128, 6, NUM_B), 256, 0, stream>>>(x, y, xb, yb);

  dim3 gg(3, 128, NUM_B), bg(256);
  dim3 gd(NUM_H / 16, NUM_C, NUM_B), bd(256);

  // branch 1: kvx = gconv(conv(x))
  conv1x1_gemm<0><<<gg, bg, 0, stream>>>(xb, nullptr, Wpk + 1 * 73728, conv_b[1], z);
  gconv3_dw<<<gd, bd, 0, stream>>>(z, dw_w[1], dw_b[1], qkv1);
  // branch 2: kvy = gconv(conv(y))
  conv1x1_gemm<0><<<gg, bg, 0, stream>>>(yb, nullptr, Wpk + 2 * 73728, conv_b[2], z);
  gconv3_dw<<<gd, bd, 0, stream>>>(z, dw_w[2], dw_b[2], qkv2);
  // branch 0: q = gconv(conv(x+y)) — writes over xb/yb (both dead now)
  conv1x1_gemm<1><<<gg, bg, 0, stream>>>(xb, yb, Wpk + 0 * 73728, conv_b[0], z);
  gconv3_dw<<<gd, bd, 0, stream>>>(z, dw_w[0], dw_b[0], qkv0);

  dots_kernel<<<dim3(64, NHEADS, NUM_B), 64, 0, stream>>>(qkv0, qkv1, qkv2, dots1, dots2, norms);
  softmax_kernel<<<dim3(NUM_B * NHEADS), 64, 0, stream>>>(dots1, dots2, norms, temp, attn);
  out_kernel<<<dim3(32, NHEADS, NUM_B), 256, 0, stream>>>(qkv1, qkv2, attn, g1, g2, out);
}